// Round 5
// baseline (642.058 us; speedup 1.0000x reference)
//
#include <hip/hip_runtime.h>
#include <hip/hip_bf16.h>
#include <math.h>

#define B_  4
#define L_  2048
#define D_  1024
#define H_  16
#define HS_ 64
#define SCALE 0.125f   // 1/sqrt(64)

typedef unsigned short ushort_t;
typedef __attribute__((ext_vector_type(8))) short short8;
typedef __attribute__((ext_vector_type(4))) float f32x4;

#define MFMA __builtin_amdgcn_mfma_f32_16x16x32_bf16

static __device__ __forceinline__ ushort_t f2bf(float f) {
    union { float f; unsigned int u; } cv; cv.f = f;
    unsigned int u = cv.u;
    unsigned int r = (u + 0x7FFFu + ((u >> 16) & 1u)) >> 16;   // RNE
    return (ushort_t)r;
}
static __device__ __forceinline__ float bf2f(ushort_t h) {
    union { float f; unsigned int u; } cv; cv.u = ((unsigned int)h) << 16;
    return cv.f;
}

static __device__ __forceinline__ void gload_lds16(const ushort_t* g, ushort_t* l) {
    __builtin_amdgcn_global_load_lds(
        (const __attribute__((address_space(1))) unsigned int*)g,
        (__attribute__((address_space(3))) unsigned int*)l, 16, 0, 0);
}

// ---------------------------------------------------------------------------
// Prep kernels: fp32 -> bf16 (x, Er), fp32 -> bf16 transposed (weights)
// ---------------------------------------------------------------------------
__global__ __launch_bounds__(256)
void conv_to_bf16(const float* __restrict__ x, ushort_t* __restrict__ xb)
{
    const size_t i = (size_t)blockIdx.x * 256 + threadIdx.x;   // 8 elems/thread
    const float4* src = (const float4*)x + i * 2;
    float4 a = src[0], b = src[1];
    ushort_t o[8] = {f2bf(a.x), f2bf(a.y), f2bf(a.z), f2bf(a.w),
                     f2bf(b.x), f2bf(b.y), f2bf(b.z), f2bf(b.w)};
    *(uint4*)(xb + i * 8) = *(uint4*)o;
}

__global__ void zero_u32(unsigned int* __restrict__ p) { *p = 0u; }

__global__ __launch_bounds__(256)
void transpose_to_bf16(const float* __restrict__ W, ushort_t* __restrict__ Wt,
                       int K, int N)   // W:[K][N] -> Wt:[N][K]
{
    __shared__ ushort_t tile[64][65];
    const int tid = threadIdx.x;
    const int n0 = blockIdx.x * 64, k0 = blockIdx.y * 64;
#pragma unroll
    for (int s = 0; s < 16; ++s) {
        const int idx = s * 256 + tid;
        const int kl = idx >> 6, nl = idx & 63;
        tile[nl][kl] = f2bf(W[(size_t)(k0 + kl) * N + n0 + nl]);
    }
    __syncthreads();
#pragma unroll
    for (int s = 0; s < 8; ++s) {
        const int idx = s * 256 + tid;
        const int nl = idx >> 5, kc = idx & 31;
        const unsigned int vlo = tile[nl][kc * 2];
        const unsigned int vhi = tile[nl][kc * 2 + 1];
        *(unsigned int*)(Wt + (size_t)(n0 + nl) * K + k0 + kc * 2) =
            vlo | (vhi << 16);
    }
}

// ---------------------------------------------------------------------------
// m97-style bf16 MFMA GEMM: C[M][N] = A[M][K] @ Bt[N][K]^T  (unchanged)
// ---------------------------------------------------------------------------
__global__ __launch_bounds__(256)
void qkv_mfma(const ushort_t* __restrict__ A, const ushort_t* __restrict__ Bt,
              const float* __restrict__ bias, ushort_t* __restrict__ qkv)
{
    __shared__ __align__(16) ushort_t As[128 * 64];
    __shared__ __align__(16) ushort_t Bs[128 * 64];

    const int tid = threadIdx.x;
    const int w = tid >> 6, lane = tid & 63, quad = lane >> 4, lcol = lane & 15;
    const int wr = w >> 1, wc = w & 1;
    const int m0 = blockIdx.y * 128, n0 = blockIdx.x * 128;
    const int K = D_;

    const int srow = tid >> 3;
    const int cg = (tid & 7) ^ (srow & 7);
    const ushort_t* gA = A + (size_t)(m0 + srow) * K + cg * 8;
    const ushort_t* gB = Bt + (size_t)(n0 + srow) * K + cg * 8;
    ushort_t* lA = As + tid * 8;
    ushort_t* lB = Bs + tid * 8;

    const int cs0 = ((quad) ^ (lcol & 7)) * 8;
    const int cs1 = ((4 + quad) ^ (lcol & 7)) * 8;

    f32x4 acc[4][4];
#pragma unroll
    for (int i = 0; i < 4; ++i)
#pragma unroll
        for (int j = 0; j < 4; ++j) acc[i][j] = (f32x4){0, 0, 0, 0};

    for (int k0 = 0; k0 < K; k0 += 64) {
        __syncthreads();
#pragma unroll
        for (int s = 0; s < 4; ++s) {
            gload_lds16(gA + k0 + (size_t)s * 32 * K, lA + s * 2048);
            gload_lds16(gB + k0 + (size_t)s * 32 * K, lB + s * 2048);
        }
        __syncthreads();
#pragma unroll
        for (int kk = 0; kk < 2; ++kk) {
            const int cs = kk ? cs1 : cs0;
            short8 af[4], bf[4];
#pragma unroll
            for (int i = 0; i < 4; ++i)
                af[i] = *(const short8*)&As[(wr * 64 + i * 16 + lcol) * 64 + cs];
#pragma unroll
            for (int j = 0; j < 4; ++j)
                bf[j] = *(const short8*)&Bs[(wc * 64 + j * 16 + lcol) * 64 + cs];
#pragma unroll
            for (int i = 0; i < 4; ++i)
#pragma unroll
                for (int j = 0; j < 4; ++j)
                    acc[i][j] = MFMA(af[i], bf[j], acc[i][j], 0, 0, 0);
        }
    }

    const size_t per = (size_t)B_ * H_ * L_ * HS_;
#pragma unroll
    for (int j = 0; j < 4; ++j) {
        const int col = n0 + wc * 64 + j * 16 + lcol;
        const float bv = bias[col];
        const int sel = col >> 10;
        const int within = col & 1023;
        const int hh = within >> 6, hs = within & 63;
        ushort_t* base = qkv + (size_t)sel * per;
#pragma unroll
        for (int i = 0; i < 4; ++i) {
#pragma unroll
            for (int reg = 0; reg < 4; ++reg) {
                const int row = m0 + wr * 64 + i * 16 + quad * 4 + reg;
                const int bb = row >> 11, ll = row & 2047;
                base[(((size_t)(bb * H_ + hh)) * L_ + ll) * HS_ + hs] =
                    f2bf(acc[i][j][reg] + bv);
            }
        }
    }
}

__global__ __launch_bounds__(256)
void proj_mfma(const ushort_t* __restrict__ A, const ushort_t* __restrict__ Bt,
               const float* __restrict__ bias, float* __restrict__ C)
{
    __shared__ __align__(16) ushort_t As[128 * 64];
    __shared__ __align__(16) ushort_t Bs[128 * 64];

    const int tid = threadIdx.x;
    const int w = tid >> 6, lane = tid & 63, quad = lane >> 4, lcol = lane & 15;
    const int wr = w >> 1, wc = w & 1;
    const int m0 = blockIdx.y * 128, n0 = blockIdx.x * 128;
    const int K = D_;
    const int N = D_;

    const int srow = tid >> 3;
    const int cg = (tid & 7) ^ (srow & 7);
    const ushort_t* gA = A + (size_t)(m0 + srow) * K + cg * 8;
    const ushort_t* gB = Bt + (size_t)(n0 + srow) * K + cg * 8;
    ushort_t* lA = As + tid * 8;
    ushort_t* lB = Bs + tid * 8;

    const int cs0 = ((quad) ^ (lcol & 7)) * 8;
    const int cs1 = ((4 + quad) ^ (lcol & 7)) * 8;

    f32x4 acc[4][4];
#pragma unroll
    for (int i = 0; i < 4; ++i)
#pragma unroll
        for (int j = 0; j < 4; ++j) acc[i][j] = (f32x4){0, 0, 0, 0};

    for (int k0 = 0; k0 < K; k0 += 64) {
        __syncthreads();
#pragma unroll
        for (int s = 0; s < 4; ++s) {
            gload_lds16(gA + k0 + (size_t)s * 32 * K, lA + s * 2048);
            gload_lds16(gB + k0 + (size_t)s * 32 * K, lB + s * 2048);
        }
        __syncthreads();
#pragma unroll
        for (int kk = 0; kk < 2; ++kk) {
            const int cs = kk ? cs1 : cs0;
            short8 af[4], bf[4];
#pragma unroll
            for (int i = 0; i < 4; ++i)
                af[i] = *(const short8*)&As[(wr * 64 + i * 16 + lcol) * 64 + cs];
#pragma unroll
            for (int j = 0; j < 4; ++j)
                bf[j] = *(const short8*)&Bs[(wc * 64 + j * 16 + lcol) * 64 + cs];
#pragma unroll
            for (int i = 0; i < 4; ++i)
#pragma unroll
                for (int j = 0; j < 4; ++j)
                    acc[i][j] = MFMA(af[i], bf[j], acc[i][j], 0, 0, 0);
        }
    }

#pragma unroll
    for (int j = 0; j < 4; ++j) {
        const int col = n0 + wc * 64 + j * 16 + lcol;
        const float bv = bias[col];
#pragma unroll
        for (int i = 0; i < 4; ++i) {
#pragma unroll
            for (int reg = 0; reg < 4; ++reg) {
                const int row = m0 + wr * 64 + i * 16 + quad * 4 + reg;
                C[(size_t)row * N + col] = acc[i][j][reg] + bv;
            }
        }
    }
}

// ---------------------------------------------------------------------------
// MFMA flash attention, v6: persistent blocks + K-in-registers.
//  * K fragments loaded DIRECT global -> regs (kf[8], single-buffered erf-style
//    prefetch: consumed by this iter's score MFMAs, reloaded for kt+1 right
//    after -> a full iteration of latency cover; 64B-coalesced, L2-resident).
//    Removes Kd LDS (-16 KB) and 8 ds_read_b128 + 2 global_load_lds per iter.
//  * Row-sum of P via ones-MFMA on the already-built P fragments: kills the
//    4-deep shfl sum tree per reg (-16 shfl/iter, shorter softmax chain).
//  * LDS 50.7 -> 33.8 KB => 4 blocks/CU; PERSIST 1024; launch_bounds(256,4).
// ---------------------------------------------------------------------------
#define QT 64
#define KT 64
#define NITEMS (B_ * H_ * (L_ / QT))   // 2048
#define PERSIST 1024

__global__ __launch_bounds__(256, 4)
void attn_mfma(const ushort_t* __restrict__ q, const ushort_t* __restrict__ k,
               const ushort_t* __restrict__ v, const ushort_t* __restrict__ Erb,
               unsigned int* __restrict__ ctr, ushort_t* __restrict__ y)
{
    __shared__ __align__(16) ushort_t Vt[2][64 * 64];   // [hs][key], swizzled
    __shared__ __align__(16) ushort_t EBuf[64][136];    // rolling QEr + P alias
    __shared__ int s_item;

    const int tid  = threadIdx.x;
    const int w    = tid >> 6;
    const int lane = tid & 63;
    const int quad = lane >> 4;
    const int lcol = lane & 15;
    const int rw   = w * 16 + quad * 4;

    // V transpose-staging constants: thread -> (key pair, hs block)
    const int vkp = (tid & 31) * 2;                // key pair base (even)
    const int vhb = (tid >> 5) * 8;                // hs block
    const int vkc = vkp >> 3, vks = vkp & 7;

    const short8 ones8 = {(short)0x3F80, (short)0x3F80, (short)0x3F80, (short)0x3F80,
                          (short)0x3F80, (short)0x3F80, (short)0x3F80, (short)0x3F80};

    for (;;) {
        if (tid == 0) s_item = (int)atomicAdd(ctr, 1u);
        __syncthreads();                 // broadcast item; also fences LDS reuse
        const int idx = s_item;
        if (idx >= NITEMS) break;

        // decode: windows of 8 bh x 32 qt, heavy-first within window
        const int wnd = idx >> 8;                 // 0..7
        const int sub = idx & 255;
        const int qt  = 31 - (sub >> 3);
        const int bh  = wnd * 8 + (sub & 7);
        const int qi0 = qt * QT;
        const int bb  = bh >> 4;
        const int hh  = bh & 15;
        const int cband = L_ - QT - qi0;

        const ushort_t* qp = q + (size_t)bh * L_ * HS_;
        const ushort_t* kp = k + (size_t)bh * L_ * HS_;
        const ushort_t* vp = v + (size_t)bh * L_ * HS_;

        // Q fragments (one-time per item, direct from global)
        const ushort_t* qrow = qp + (size_t)(qi0 + w * 16 + lcol) * HS_;
        const short8 aq0 = *(const short8*)(qrow + quad * 8);
        const short8 aq1 = *(const short8*)(qrow + 32 + quad * 8);

        // ---- prologue ----
        // EBuf chunk 0 via direct-global Er MFMAs (one-time)
        {
            const ushort_t* eb = Erb + (size_t)cband * HS_;
            f32x4 e0 = {0,0,0,0}, e1 = {0,0,0,0}, e2 = {0,0,0,0}, e3 = {0,0,0,0};
            e0 = MFMA(aq0, *(const short8*)(eb + (size_t)( 0 + lcol) * HS_ +      quad * 8), e0, 0,0,0);
            e1 = MFMA(aq0, *(const short8*)(eb + (size_t)(16 + lcol) * HS_ +      quad * 8), e1, 0,0,0);
            e2 = MFMA(aq0, *(const short8*)(eb + (size_t)(32 + lcol) * HS_ +      quad * 8), e2, 0,0,0);
            e3 = MFMA(aq0, *(const short8*)(eb + (size_t)(48 + lcol) * HS_ +      quad * 8), e3, 0,0,0);
            e0 = MFMA(aq1, *(const short8*)(eb + (size_t)( 0 + lcol) * HS_ + 32 + quad * 8), e0, 0,0,0);
            e1 = MFMA(aq1, *(const short8*)(eb + (size_t)(16 + lcol) * HS_ + 32 + quad * 8), e1, 0,0,0);
            e2 = MFMA(aq1, *(const short8*)(eb + (size_t)(32 + lcol) * HS_ + 32 + quad * 8), e2, 0,0,0);
            e3 = MFMA(aq1, *(const short8*)(eb + (size_t)(48 + lcol) * HS_ + 32 + quad * 8), e3, 0,0,0);
#pragma unroll
            for (int reg = 0; reg < 4; ++reg) {
                EBuf[rw + reg][ 0 + lcol] = f2bf(e0[reg]);
                EBuf[rw + reg][16 + lcol] = f2bf(e1[reg]);
                EBuf[rw + reg][32 + lcol] = f2bf(e2[reg]);
                EBuf[rw + reg][48 + lcol] = f2bf(e3[reg]);
            }
        }
        // K fragments for tile 0 -> regs
        short8 kf[8];
#pragma unroll
        for (int nt = 0; nt < 4; ++nt) {
            const ushort_t* p = kp + (size_t)(nt * 16 + lcol) * HS_ + quad * 8;
            kf[nt * 2]     = *(const short8*)p;
            kf[nt * 2 + 1] = *(const short8*)(p + 32);
        }
        // Er fragments for chunk 1 -> regs (row-clamped)
        short8 erf[8];
#pragma unroll
        for (int nt = 0; nt < 4; ++nt) {
            int r = cband + 64 + nt * 16 + lcol;
            if (r > L_ - 1) r = L_ - 1;
            const ushort_t* p = Erb + (size_t)r * HS_ + quad * 8;
            erf[nt * 2]     = *(const short8*)p;
            erf[nt * 2 + 1] = *(const short8*)(p + 32);
        }
        // V tile 0 -> Vt[0] (sync reg round-trip, packed b32 swizzled write)
        {
            const ushort_t* src = vp + (size_t)vkp * HS_ + vhb;
            uint4 a = *(const uint4*)src;
            uint4 b = *(const uint4*)(src + HS_);
            const ushort_t* pa = (const ushort_t*)&a;
            const ushort_t* pb = (const ushort_t*)&b;
#pragma unroll
            for (int u = 0; u < 8; ++u) {
                const int hs = vhb + u;
                const int f = ((hs >> 3) & 7) ^ (hs & 7);
                const unsigned int val = (unsigned int)pa[u] | ((unsigned int)pb[u] << 16);
                *(unsigned int*)&Vt[0][hs * 64 + ((vkc ^ f) << 3) + vks] = val;
            }
        }
        // V tile 1 -> regs (unused if qt==0; rows always in-bounds)
        uint4 va, vb;
        {
            const ushort_t* src = vp + (size_t)(KT + vkp) * HS_ + vhb;
            va = *(const uint4*)src; vb = *(const uint4*)(src + HS_);
        }

        f32x4 O[4];
#pragma unroll
        for (int nt = 0; nt < 4; ++nt) O[nt] = (f32x4){0, 0, 0, 0};
        float m_r[4] = {-INFINITY, -INFINITY, -INFINITY, -INFINITY};
        float l_r[4] = {0, 0, 0, 0};

        for (int kt = 0; kt <= qt; ++kt) {
            const int kj0 = kt * KT;
            const int cur = kt & 1, nxt = cur ^ 1;

            __syncthreads();   // orders Vt buffers across the block

            if (kt < qt) {
                // write Vt[nxt] <- V tile kt+1 (regs loaded last iter)
                {
                    const ushort_t* pa = (const ushort_t*)&va;
                    const ushort_t* pb = (const ushort_t*)&vb;
#pragma unroll
                    for (int u = 0; u < 8; ++u) {
                        const int hs = vhb + u;
                        const int f = ((hs >> 3) & 7) ^ (hs & 7);
                        const unsigned int val = (unsigned int)pa[u] | ((unsigned int)pb[u] << 16);
                        *(unsigned int*)&Vt[nxt][hs * 64 + ((vkc ^ f) << 3) + vks] = val;
                    }
                }
                // issue V tile kt+2 -> regs (row-clamped)
                {
                    int kj2 = (kt + 2) * KT;
                    if (kj2 > L_ - KT) kj2 = L_ - KT;
                    const ushort_t* src = vp + (size_t)(kj2 + vkp) * HS_ + vhb;
                    va = *(const uint4*)src; vb = *(const uint4*)(src + HS_);
                }
            }

            // ---- QEr chunk kt+1 from erf regs ----
            f32x4 e0 = {0,0,0,0}, e1 = {0,0,0,0}, e2 = {0,0,0,0}, e3 = {0,0,0,0};
            e0 = MFMA(aq0, erf[0], e0, 0,0,0);
            e1 = MFMA(aq0, erf[2], e1, 0,0,0);
            e2 = MFMA(aq0, erf[4], e2, 0,0,0);
            e3 = MFMA(aq0, erf[6], e3, 0,0,0);
            e0 = MFMA(aq1, erf[1], e0, 0,0,0);
            e1 = MFMA(aq1, erf[3], e1, 0,0,0);
            e2 = MFMA(aq1, erf[5], e2, 0,0,0);
            e3 = MFMA(aq1, erf[7], e3, 0,0,0);

            // reload erf <- Er fragments for chunk kt+2 (WAR; lands next iter)
            {
                const int ebase = cband + (kt + 2) * 64;
#pragma unroll
                for (int nt = 0; nt < 4; ++nt) {
                    int r = ebase + nt * 16 + lcol;
                    if (r > L_ - 1) r = L_ - 1;
                    const ushort_t* p = Erb + (size_t)r * HS_ + quad * 8;
                    erf[nt * 2]     = *(const short8*)p;
                    erf[nt * 2 + 1] = *(const short8*)(p + 32);
                }
            }

            {
                const int par = nxt * 64;   // chunk kt+1
#pragma unroll
                for (int reg = 0; reg < 4; ++reg) {
                    EBuf[rw + reg][par +  0 + lcol] = f2bf(e0[reg]);
                    EBuf[rw + reg][par + 16 + lcol] = f2bf(e1[reg]);
                    EBuf[rw + reg][par + 32 + lcol] = f2bf(e2[reg]);
                    EBuf[rw + reg][par + 48 + lcol] = f2bf(e3[reg]);
                }
            }

            // ---- scores from kf regs ----
            f32x4 s0 = {0,0,0,0}, s1 = {0,0,0,0}, s2 = {0,0,0,0}, s3 = {0,0,0,0};
            s0 = MFMA(aq0, kf[0], s0, 0,0,0);
            s1 = MFMA(aq0, kf[2], s1, 0,0,0);
            s2 = MFMA(aq0, kf[4], s2, 0,0,0);
            s3 = MFMA(aq0, kf[6], s3, 0,0,0);
            s0 = MFMA(aq1, kf[1], s0, 0,0,0);
            s1 = MFMA(aq1, kf[3], s1, 0,0,0);
            s2 = MFMA(aq1, kf[5], s2, 0,0,0);
            s3 = MFMA(aq1, kf[7], s3, 0,0,0);

            // reload kf <- K fragments for tile kt+1 (WAR; lands next iter)
            if (kt < qt) {
                const ushort_t* kb = kp + (size_t)(kt + 1) * KT * HS_;
#pragma unroll
                for (int nt = 0; nt < 4; ++nt) {
                    const ushort_t* p = kb + (size_t)(nt * 16 + lcol) * HS_ + quad * 8;
                    kf[nt * 2]     = *(const short8*)p;
                    kf[nt * 2 + 1] = *(const short8*)(p + 32);
                }
            }

            float p_[4][4];
            float al[4];
            const float sq[4][4] = {
                {s0[0], s0[1], s0[2], s0[3]},
                {s1[0], s1[1], s1[2], s1[3]},
                {s2[0], s2[1], s2[2], s2[3]},
                {s3[0], s3[1], s3[2], s3[3]}};
#pragma unroll
            for (int reg = 0; reg < 4; ++reg) {
                const int r = w * 16 + quad * 4 + reg;
                float scr[4];
#pragma unroll
                for (int nt = 0; nt < 4; ++nt) {
                    const int jl = nt * 16 + lcol;
                    const int c = (63 - r + jl + kj0) & 127;
                    float sv = (sq[nt][reg] + bf2f(EBuf[r][c])) * SCALE;
                    if (kt == qt && jl > r) sv = -INFINITY;
                    scr[nt] = sv;
                }
                float mx = fmaxf(fmaxf(scr[0], scr[1]), fmaxf(scr[2], scr[3]));
                mx = fmaxf(mx, __shfl_xor(mx, 1));
                mx = fmaxf(mx, __shfl_xor(mx, 2));
                mx = fmaxf(mx, __shfl_xor(mx, 4));
                mx = fmaxf(mx, __shfl_xor(mx, 8));
                const float nm = fmaxf(m_r[reg], mx);
                const float a_ = __expf(m_r[reg] - nm);
                m_r[reg] = nm;
#pragma unroll
                for (int nt = 0; nt < 4; ++nt)
                    p_[nt][reg] = __expf(scr[nt] - nm);
                al[reg] = a_;
            }
#pragma unroll
            for (int nt = 0; nt < 4; ++nt)
#pragma unroll
                for (int reg = 0; reg < 4; ++reg) O[nt][reg] *= al[reg];

            // P: wave-private round-trip through EBuf's dead chunk-half (par cur)
            {
#pragma unroll
                for (int reg = 0; reg < 4; ++reg) {
                    ushort_t* pr = &EBuf[rw + reg][cur * 64];
                    pr[ 0 + lcol] = f2bf(p_[0][reg]);
                    pr[16 + lcol] = f2bf(p_[1][reg]);
                    pr[32 + lcol] = f2bf(p_[2][reg]);
                    pr[48 + lcol] = f2bf(p_[3][reg]);
                }
            }
            const short8 ap0 = *(const short8*)&EBuf[w * 16 + lcol][cur * 64 + quad * 8];
            const short8 ap1 = *(const short8*)&EBuf[w * 16 + lcol][cur * 64 + 32 + quad * 8];

            // row-sum of P via ones-MFMA (replaces shfl sum tree)
            f32x4 lacc = {0, 0, 0, 0};
            lacc = MFMA(ap0, ones8, lacc, 0, 0, 0);
            lacc = MFMA(ap1, ones8, lacc, 0, 0, 0);
#pragma unroll
            for (int reg = 0; reg < 4; ++reg)
                l_r[reg] = l_r[reg] * al[reg] + lacc[reg];

            // PV: swizzled Vt[cur] fragment reads
            {
#pragma unroll
                for (int nt = 0; nt < 4; ++nt) {
                    const int hs = nt * 16 + lcol;
                    const int f = ((hs >> 3) & 7) ^ (hs & 7);
                    const short8 bv0 = *(const short8*)&Vt[cur][hs * 64 + ((quad ^ f) << 3)];
                    const short8 bv1 = *(const short8*)&Vt[cur][hs * 64 + (((4 + quad) ^ f) << 3)];
                    O[nt] = MFMA(ap0, bv0, O[nt], 0, 0, 0);
                    O[nt] = MFMA(ap1, bv1, O[nt], 0, 0, 0);
                }
            }
        }

        float inv[4];
#pragma unroll
        for (int reg = 0; reg < 4; ++reg) inv[reg] = 1.f / l_r[reg];
#pragma unroll
        for (int nt = 0; nt < 4; ++nt) {
#pragma unroll
            for (int reg = 0; reg < 4; ++reg) {
                const int r = w * 16 + quad * 4 + reg;
                y[(((size_t)bb * L_ + qi0 + r) * H_ + hh) * HS_ + nt * 16 + lcol] =
                    f2bf(O[nt][reg] * inv[reg]);
            }
        }
    }
}

// ---------------------------------------------------------------------------
extern "C" void kernel_launch(void* const* d_in, const int* in_sizes, int n_in,
                              void* d_out, int out_size, void* d_ws, size_t ws_size,
                              hipStream_t stream)
{
    const float* x      = (const float*)d_in[0];   // [B,L,D]
    const float* W_attn = (const float*)d_in[1];   // [D,3D]
    const float* b_attn = (const float*)d_in[2];   // [3D]
    const float* W_proj = (const float*)d_in[3];   // [D,D]
    const float* b_proj = (const float*)d_in[4];   // [D]
    const float* Er     = (const float*)d_in[5];   // [L,HS] fp32
    float* out = (float*)d_out;

    const size_t per = (size_t)B_ * H_ * L_ * HS_;   // 8388608
    ushort_t* qb  = (ushort_t*)d_ws;                 // bf16 q|k|v
    ushort_t* kb  = qb + per;
    ushort_t* vb  = kb + per;
    ushort_t* yb  = vb + per;                        // bf16 [B][L][D]
    ushort_t* xb  = yb + per;                        // bf16 x
    ushort_t* wat = xb + per;                        // W_attn^T bf16 [3072][1024]
    ushort_t* wpt = wat + (size_t)3 * D_ * D_;       // W_proj^T bf16 [1024][1024]
    ushort_t* erb = wpt + (size_t)D_ * D_;           // Er bf16 [L][HS]
    unsigned int* ctr = (unsigned int*)(erb + (size_t)L_ * HS_);  // work counter

    dim3 blk(256);

    conv_to_bf16<<<dim3((B_ * L_ * D_) / 2048), blk, 0, stream>>>(x, xb);
    conv_to_bf16<<<dim3((L_ * HS_) / 2048), blk, 0, stream>>>(Er, erb);
    zero_u32<<<dim3(1), dim3(1), 0, stream>>>(ctr);
    transpose_to_bf16<<<dim3(3 * D_ / 64, D_ / 64), blk, 0, stream>>>(W_attn, wat, D_, 3 * D_);
    transpose_to_bf16<<<dim3(D_ / 64, D_ / 64), blk, 0, stream>>>(W_proj, wpt, D_, D_);

    qkv_mfma<<<dim3(3 * D_ / 128, B_ * L_ / 128), blk, 0, stream>>>(xb, wat, b_attn, qb);

    attn_mfma<<<dim3(PERSIST), blk, 0, stream>>>(qb, kb, vb, erb, ctr, yb);

    proj_mfma<<<dim3(D_ / 128, B_ * L_ / 128), blk, 0, stream>>>(yb, wpt, b_proj, out);
}

// Round 6
// 552.246 us; speedup vs baseline: 1.1626x; 1.1626x over previous
//
#include <hip/hip_runtime.h>
#include <hip/hip_bf16.h>
#include <math.h>

#define B_  4
#define L_  2048
#define D_  1024
#define H_  16
#define HS_ 64
#define SCALE 0.125f   // 1/sqrt(64)

typedef unsigned short ushort_t;
typedef __attribute__((ext_vector_type(8))) short short8;
typedef __attribute__((ext_vector_type(4))) float f32x4;

#define MFMA __builtin_amdgcn_mfma_f32_16x16x32_bf16

static __device__ __forceinline__ ushort_t f2bf(float f) {
    union { float f; unsigned int u; } cv; cv.f = f;
    unsigned int u = cv.u;
    unsigned int r = (u + 0x7FFFu + ((u >> 16) & 1u)) >> 16;   // RNE
    return (ushort_t)r;
}
static __device__ __forceinline__ float bf2f(ushort_t h) {
    union { float f; unsigned int u; } cv; cv.u = ((unsigned int)h) << 16;
    return cv.f;
}

static __device__ __forceinline__ void gload_lds16(const ushort_t* g, ushort_t* l) {
    __builtin_amdgcn_global_load_lds(
        (const __attribute__((address_space(1))) unsigned int*)g,
        (__attribute__((address_space(3))) unsigned int*)l, 16, 0, 0);
}

// ---------------------------------------------------------------------------
// Prep kernels: fp32 -> bf16 (x, Er), fp32 -> bf16 transposed (weights)
// ---------------------------------------------------------------------------
__global__ __launch_bounds__(256)
void conv_to_bf16(const float* __restrict__ x, ushort_t* __restrict__ xb)
{
    const size_t i = (size_t)blockIdx.x * 256 + threadIdx.x;   // 8 elems/thread
    const float4* src = (const float4*)x + i * 2;
    float4 a = src[0], b = src[1];
    ushort_t o[8] = {f2bf(a.x), f2bf(a.y), f2bf(a.z), f2bf(a.w),
                     f2bf(b.x), f2bf(b.y), f2bf(b.z), f2bf(b.w)};
    *(uint4*)(xb + i * 8) = *(uint4*)o;
}

__global__ void zero_u32(unsigned int* __restrict__ p) { *p = 0u; }

__global__ __launch_bounds__(256)
void transpose_to_bf16(const float* __restrict__ W, ushort_t* __restrict__ Wt,
                       int K, int N)   // W:[K][N] -> Wt:[N][K]
{
    __shared__ ushort_t tile[64][65];
    const int tid = threadIdx.x;
    const int n0 = blockIdx.x * 64, k0 = blockIdx.y * 64;
#pragma unroll
    for (int s = 0; s < 16; ++s) {
        const int idx = s * 256 + tid;
        const int kl = idx >> 6, nl = idx & 63;
        tile[nl][kl] = f2bf(W[(size_t)(k0 + kl) * N + n0 + nl]);
    }
    __syncthreads();
#pragma unroll
    for (int s = 0; s < 8; ++s) {
        const int idx = s * 256 + tid;
        const int nl = idx >> 5, kc = idx & 31;
        const unsigned int vlo = tile[nl][kc * 2];
        const unsigned int vhi = tile[nl][kc * 2 + 1];
        *(unsigned int*)(Wt + (size_t)(n0 + nl) * K + k0 + kc * 2) =
            vlo | (vhi << 16);
    }
}

// ---------------------------------------------------------------------------
// m97-style bf16 MFMA GEMM: C[M][N] = A[M][K] @ Bt[N][K]^T  (unchanged)
// ---------------------------------------------------------------------------
__global__ __launch_bounds__(256)
void qkv_mfma(const ushort_t* __restrict__ A, const ushort_t* __restrict__ Bt,
              const float* __restrict__ bias, ushort_t* __restrict__ qkv)
{
    __shared__ __align__(16) ushort_t As[128 * 64];
    __shared__ __align__(16) ushort_t Bs[128 * 64];

    const int tid = threadIdx.x;
    const int w = tid >> 6, lane = tid & 63, quad = lane >> 4, lcol = lane & 15;
    const int wr = w >> 1, wc = w & 1;
    const int m0 = blockIdx.y * 128, n0 = blockIdx.x * 128;
    const int K = D_;

    const int srow = tid >> 3;
    const int cg = (tid & 7) ^ (srow & 7);
    const ushort_t* gA = A + (size_t)(m0 + srow) * K + cg * 8;
    const ushort_t* gB = Bt + (size_t)(n0 + srow) * K + cg * 8;
    ushort_t* lA = As + tid * 8;
    ushort_t* lB = Bs + tid * 8;

    const int cs0 = ((quad) ^ (lcol & 7)) * 8;
    const int cs1 = ((4 + quad) ^ (lcol & 7)) * 8;

    f32x4 acc[4][4];
#pragma unroll
    for (int i = 0; i < 4; ++i)
#pragma unroll
        for (int j = 0; j < 4; ++j) acc[i][j] = (f32x4){0, 0, 0, 0};

    for (int k0 = 0; k0 < K; k0 += 64) {
        __syncthreads();
#pragma unroll
        for (int s = 0; s < 4; ++s) {
            gload_lds16(gA + k0 + (size_t)s * 32 * K, lA + s * 2048);
            gload_lds16(gB + k0 + (size_t)s * 32 * K, lB + s * 2048);
        }
        __syncthreads();
#pragma unroll
        for (int kk = 0; kk < 2; ++kk) {
            const int cs = kk ? cs1 : cs0;
            short8 af[4], bf[4];
#pragma unroll
            for (int i = 0; i < 4; ++i)
                af[i] = *(const short8*)&As[(wr * 64 + i * 16 + lcol) * 64 + cs];
#pragma unroll
            for (int j = 0; j < 4; ++j)
                bf[j] = *(const short8*)&Bs[(wc * 64 + j * 16 + lcol) * 64 + cs];
#pragma unroll
            for (int i = 0; i < 4; ++i)
#pragma unroll
                for (int j = 0; j < 4; ++j)
                    acc[i][j] = MFMA(af[i], bf[j], acc[i][j], 0, 0, 0);
        }
    }

    const size_t per = (size_t)B_ * H_ * L_ * HS_;
#pragma unroll
    for (int j = 0; j < 4; ++j) {
        const int col = n0 + wc * 64 + j * 16 + lcol;
        const float bv = bias[col];
        const int sel = col >> 10;
        const int within = col & 1023;
        const int hh = within >> 6, hs = within & 63;
        ushort_t* base = qkv + (size_t)sel * per;
#pragma unroll
        for (int i = 0; i < 4; ++i) {
#pragma unroll
            for (int reg = 0; reg < 4; ++reg) {
                const int row = m0 + wr * 64 + i * 16 + quad * 4 + reg;
                const int bb = row >> 11, ll = row & 2047;
                base[(((size_t)(bb * H_ + hh)) * L_ + ll) * HS_ + hs] =
                    f2bf(acc[i][j][reg] + bv);
            }
        }
    }
}

__global__ __launch_bounds__(256)
void proj_mfma(const ushort_t* __restrict__ A, const ushort_t* __restrict__ Bt,
               const float* __restrict__ bias, float* __restrict__ C)
{
    __shared__ __align__(16) ushort_t As[128 * 64];
    __shared__ __align__(16) ushort_t Bs[128 * 64];

    const int tid = threadIdx.x;
    const int w = tid >> 6, lane = tid & 63, quad = lane >> 4, lcol = lane & 15;
    const int wr = w >> 1, wc = w & 1;
    const int m0 = blockIdx.y * 128, n0 = blockIdx.x * 128;
    const int K = D_;
    const int N = D_;

    const int srow = tid >> 3;
    const int cg = (tid & 7) ^ (srow & 7);
    const ushort_t* gA = A + (size_t)(m0 + srow) * K + cg * 8;
    const ushort_t* gB = Bt + (size_t)(n0 + srow) * K + cg * 8;
    ushort_t* lA = As + tid * 8;
    ushort_t* lB = Bs + tid * 8;

    const int cs0 = ((quad) ^ (lcol & 7)) * 8;
    const int cs1 = ((4 + quad) ^ (lcol & 7)) * 8;

    f32x4 acc[4][4];
#pragma unroll
    for (int i = 0; i < 4; ++i)
#pragma unroll
        for (int j = 0; j < 4; ++j) acc[i][j] = (f32x4){0, 0, 0, 0};

    for (int k0 = 0; k0 < K; k0 += 64) {
        __syncthreads();
#pragma unroll
        for (int s = 0; s < 4; ++s) {
            gload_lds16(gA + k0 + (size_t)s * 32 * K, lA + s * 2048);
            gload_lds16(gB + k0 + (size_t)s * 32 * K, lB + s * 2048);
        }
        __syncthreads();
#pragma unroll
        for (int kk = 0; kk < 2; ++kk) {
            const int cs = kk ? cs1 : cs0;
            short8 af[4], bf[4];
#pragma unroll
            for (int i = 0; i < 4; ++i)
                af[i] = *(const short8*)&As[(wr * 64 + i * 16 + lcol) * 64 + cs];
#pragma unroll
            for (int j = 0; j < 4; ++j)
                bf[j] = *(const short8*)&Bs[(wc * 64 + j * 16 + lcol) * 64 + cs];
#pragma unroll
            for (int i = 0; i < 4; ++i)
#pragma unroll
                for (int j = 0; j < 4; ++j)
                    acc[i][j] = MFMA(af[i], bf[j], acc[i][j], 0, 0, 0);
        }
    }

#pragma unroll
    for (int j = 0; j < 4; ++j) {
        const int col = n0 + wc * 64 + j * 16 + lcol;
        const float bv = bias[col];
#pragma unroll
        for (int i = 0; i < 4; ++i) {
#pragma unroll
            for (int reg = 0; reg < 4; ++reg) {
                const int row = m0 + wr * 64 + i * 16 + quad * 4 + reg;
                C[(size_t)row * N + col] = acc[i][j][reg] + bv;
            }
        }
    }
}

// ---------------------------------------------------------------------------
// MFMA flash attention, v7: v6 content with the spill fixed.
//  * v6's regression was __launch_bounds__(256,4): VGPR cap 128 < ~150 needed
//    -> scratch spill (WRITE_SIZE 31->106 MB, VGPR_Count 64 anomaly).
//  * v7: launch_bounds(256,3) (cap 168, fits), PERSIST 768 (3 blocks/CU).
//    Same occupancy as the 273 us R4 kernel, minus Kd LDS traffic
//    (-8 ds_read_b128, -2 global_load_lds per iter) and minus the shfl
//    sum tree (ones-MFMA row-sum).
// ---------------------------------------------------------------------------
#define QT 64
#define KT 64
#define NITEMS (B_ * H_ * (L_ / QT))   // 2048
#define PERSIST 768

__global__ __launch_bounds__(256, 3)
void attn_mfma(const ushort_t* __restrict__ q, const ushort_t* __restrict__ k,
               const ushort_t* __restrict__ v, const ushort_t* __restrict__ Erb,
               unsigned int* __restrict__ ctr, ushort_t* __restrict__ y)
{
    __shared__ __align__(16) ushort_t Vt[2][64 * 64];   // [hs][key], swizzled
    __shared__ __align__(16) ushort_t EBuf[64][136];    // rolling QEr + P alias
    __shared__ int s_item;

    const int tid  = threadIdx.x;
    const int w    = tid >> 6;
    const int lane = tid & 63;
    const int quad = lane >> 4;
    const int lcol = lane & 15;
    const int rw   = w * 16 + quad * 4;

    // V transpose-staging constants: thread -> (key pair, hs block)
    const int vkp = (tid & 31) * 2;                // key pair base (even)
    const int vhb = (tid >> 5) * 8;                // hs block
    const int vkc = vkp >> 3, vks = vkp & 7;

    const short8 ones8 = {(short)0x3F80, (short)0x3F80, (short)0x3F80, (short)0x3F80,
                          (short)0x3F80, (short)0x3F80, (short)0x3F80, (short)0x3F80};

    for (;;) {
        if (tid == 0) s_item = (int)atomicAdd(ctr, 1u);
        __syncthreads();                 // broadcast item; also fences LDS reuse
        const int idx = s_item;
        if (idx >= NITEMS) break;

        // decode: windows of 8 bh x 32 qt, heavy-first within window
        const int wnd = idx >> 8;                 // 0..7
        const int sub = idx & 255;
        const int qt  = 31 - (sub >> 3);
        const int bh  = wnd * 8 + (sub & 7);
        const int qi0 = qt * QT;
        const int bb  = bh >> 4;
        const int hh  = bh & 15;
        const int cband = L_ - QT - qi0;

        const ushort_t* qp = q + (size_t)bh * L_ * HS_;
        const ushort_t* kp = k + (size_t)bh * L_ * HS_;
        const ushort_t* vp = v + (size_t)bh * L_ * HS_;

        // Q fragments (one-time per item, direct from global)
        const ushort_t* qrow = qp + (size_t)(qi0 + w * 16 + lcol) * HS_;
        const short8 aq0 = *(const short8*)(qrow + quad * 8);
        const short8 aq1 = *(const short8*)(qrow + 32 + quad * 8);

        // ---- prologue ----
        // EBuf chunk 0 via direct-global Er MFMAs (one-time)
        {
            const ushort_t* eb = Erb + (size_t)cband * HS_;
            f32x4 e0 = {0,0,0,0}, e1 = {0,0,0,0}, e2 = {0,0,0,0}, e3 = {0,0,0,0};
            e0 = MFMA(aq0, *(const short8*)(eb + (size_t)( 0 + lcol) * HS_ +      quad * 8), e0, 0,0,0);
            e1 = MFMA(aq0, *(const short8*)(eb + (size_t)(16 + lcol) * HS_ +      quad * 8), e1, 0,0,0);
            e2 = MFMA(aq0, *(const short8*)(eb + (size_t)(32 + lcol) * HS_ +      quad * 8), e2, 0,0,0);
            e3 = MFMA(aq0, *(const short8*)(eb + (size_t)(48 + lcol) * HS_ +      quad * 8), e3, 0,0,0);
            e0 = MFMA(aq1, *(const short8*)(eb + (size_t)( 0 + lcol) * HS_ + 32 + quad * 8), e0, 0,0,0);
            e1 = MFMA(aq1, *(const short8*)(eb + (size_t)(16 + lcol) * HS_ + 32 + quad * 8), e1, 0,0,0);
            e2 = MFMA(aq1, *(const short8*)(eb + (size_t)(32 + lcol) * HS_ + 32 + quad * 8), e2, 0,0,0);
            e3 = MFMA(aq1, *(const short8*)(eb + (size_t)(48 + lcol) * HS_ + 32 + quad * 8), e3, 0,0,0);
#pragma unroll
            for (int reg = 0; reg < 4; ++reg) {
                EBuf[rw + reg][ 0 + lcol] = f2bf(e0[reg]);
                EBuf[rw + reg][16 + lcol] = f2bf(e1[reg]);
                EBuf[rw + reg][32 + lcol] = f2bf(e2[reg]);
                EBuf[rw + reg][48 + lcol] = f2bf(e3[reg]);
            }
        }
        // K fragments for tile 0 -> regs
        short8 kf[8];
#pragma unroll
        for (int nt = 0; nt < 4; ++nt) {
            const ushort_t* p = kp + (size_t)(nt * 16 + lcol) * HS_ + quad * 8;
            kf[nt * 2]     = *(const short8*)p;
            kf[nt * 2 + 1] = *(const short8*)(p + 32);
        }
        // Er fragments for chunk 1 -> regs (row-clamped)
        short8 erf[8];
#pragma unroll
        for (int nt = 0; nt < 4; ++nt) {
            int r = cband + 64 + nt * 16 + lcol;
            if (r > L_ - 1) r = L_ - 1;
            const ushort_t* p = Erb + (size_t)r * HS_ + quad * 8;
            erf[nt * 2]     = *(const short8*)p;
            erf[nt * 2 + 1] = *(const short8*)(p + 32);
        }
        // V tile 0 -> Vt[0] (sync reg round-trip, packed b32 swizzled write)
        {
            const ushort_t* src = vp + (size_t)vkp * HS_ + vhb;
            uint4 a = *(const uint4*)src;
            uint4 b = *(const uint4*)(src + HS_);
            const ushort_t* pa = (const ushort_t*)&a;
            const ushort_t* pb = (const ushort_t*)&b;
#pragma unroll
            for (int u = 0; u < 8; ++u) {
                const int hs = vhb + u;
                const int f = ((hs >> 3) & 7) ^ (hs & 7);
                const unsigned int val = (unsigned int)pa[u] | ((unsigned int)pb[u] << 16);
                *(unsigned int*)&Vt[0][hs * 64 + ((vkc ^ f) << 3) + vks] = val;
            }
        }
        // V tile 1 -> regs (unused if qt==0; rows always in-bounds)
        uint4 va, vb;
        {
            const ushort_t* src = vp + (size_t)(KT + vkp) * HS_ + vhb;
            va = *(const uint4*)src; vb = *(const uint4*)(src + HS_);
        }

        f32x4 O[4];
#pragma unroll
        for (int nt = 0; nt < 4; ++nt) O[nt] = (f32x4){0, 0, 0, 0};
        float m_r[4] = {-INFINITY, -INFINITY, -INFINITY, -INFINITY};
        float l_r[4] = {0, 0, 0, 0};

        for (int kt = 0; kt <= qt; ++kt) {
            const int kj0 = kt * KT;
            const int cur = kt & 1, nxt = cur ^ 1;

            __syncthreads();   // orders Vt buffers across the block

            if (kt < qt) {
                // write Vt[nxt] <- V tile kt+1 (regs loaded last iter)
                {
                    const ushort_t* pa = (const ushort_t*)&va;
                    const ushort_t* pb = (const ushort_t*)&vb;
#pragma unroll
                    for (int u = 0; u < 8; ++u) {
                        const int hs = vhb + u;
                        const int f = ((hs >> 3) & 7) ^ (hs & 7);
                        const unsigned int val = (unsigned int)pa[u] | ((unsigned int)pb[u] << 16);
                        *(unsigned int*)&Vt[nxt][hs * 64 + ((vkc ^ f) << 3) + vks] = val;
                    }
                }
                // issue V tile kt+2 -> regs (row-clamped)
                {
                    int kj2 = (kt + 2) * KT;
                    if (kj2 > L_ - KT) kj2 = L_ - KT;
                    const ushort_t* src = vp + (size_t)(kj2 + vkp) * HS_ + vhb;
                    va = *(const uint4*)src; vb = *(const uint4*)(src + HS_);
                }
            }

            // ---- QEr chunk kt+1 from erf regs ----
            f32x4 e0 = {0,0,0,0}, e1 = {0,0,0,0}, e2 = {0,0,0,0}, e3 = {0,0,0,0};
            e0 = MFMA(aq0, erf[0], e0, 0,0,0);
            e1 = MFMA(aq0, erf[2], e1, 0,0,0);
            e2 = MFMA(aq0, erf[4], e2, 0,0,0);
            e3 = MFMA(aq0, erf[6], e3, 0,0,0);
            e0 = MFMA(aq1, erf[1], e0, 0,0,0);
            e1 = MFMA(aq1, erf[3], e1, 0,0,0);
            e2 = MFMA(aq1, erf[5], e2, 0,0,0);
            e3 = MFMA(aq1, erf[7], e3, 0,0,0);

            // reload erf <- Er fragments for chunk kt+2 (WAR; lands next iter)
            {
                const int ebase = cband + (kt + 2) * 64;
#pragma unroll
                for (int nt = 0; nt < 4; ++nt) {
                    int r = ebase + nt * 16 + lcol;
                    if (r > L_ - 1) r = L_ - 1;
                    const ushort_t* p = Erb + (size_t)r * HS_ + quad * 8;
                    erf[nt * 2]     = *(const short8*)p;
                    erf[nt * 2 + 1] = *(const short8*)(p + 32);
                }
            }

            {
                const int par = nxt * 64;   // chunk kt+1
#pragma unroll
                for (int reg = 0; reg < 4; ++reg) {
                    EBuf[rw + reg][par +  0 + lcol] = f2bf(e0[reg]);
                    EBuf[rw + reg][par + 16 + lcol] = f2bf(e1[reg]);
                    EBuf[rw + reg][par + 32 + lcol] = f2bf(e2[reg]);
                    EBuf[rw + reg][par + 48 + lcol] = f2bf(e3[reg]);
                }
            }

            // ---- scores from kf regs ----
            f32x4 s0 = {0,0,0,0}, s1 = {0,0,0,0}, s2 = {0,0,0,0}, s3 = {0,0,0,0};
            s0 = MFMA(aq0, kf[0], s0, 0,0,0);
            s1 = MFMA(aq0, kf[2], s1, 0,0,0);
            s2 = MFMA(aq0, kf[4], s2, 0,0,0);
            s3 = MFMA(aq0, kf[6], s3, 0,0,0);
            s0 = MFMA(aq1, kf[1], s0, 0,0,0);
            s1 = MFMA(aq1, kf[3], s1, 0,0,0);
            s2 = MFMA(aq1, kf[5], s2, 0,0,0);
            s3 = MFMA(aq1, kf[7], s3, 0,0,0);

            // reload kf <- K fragments for tile kt+1 (WAR; lands next iter)
            if (kt < qt) {
                const ushort_t* kb = kp + (size_t)(kt + 1) * KT * HS_;
#pragma unroll
                for (int nt = 0; nt < 4; ++nt) {
                    const ushort_t* p = kb + (size_t)(nt * 16 + lcol) * HS_ + quad * 8;
                    kf[nt * 2]     = *(const short8*)p;
                    kf[nt * 2 + 1] = *(const short8*)(p + 32);
                }
            }

            float p_[4][4];
            float al[4];
            const float sq[4][4] = {
                {s0[0], s0[1], s0[2], s0[3]},
                {s1[0], s1[1], s1[2], s1[3]},
                {s2[0], s2[1], s2[2], s2[3]},
                {s3[0], s3[1], s3[2], s3[3]}};
#pragma unroll
            for (int reg = 0; reg < 4; ++reg) {
                const int r = w * 16 + quad * 4 + reg;
                float scr[4];
#pragma unroll
                for (int nt = 0; nt < 4; ++nt) {
                    const int jl = nt * 16 + lcol;
                    const int c = (63 - r + jl + kj0) & 127;
                    float sv = (sq[nt][reg] + bf2f(EBuf[r][c])) * SCALE;
                    if (kt == qt && jl > r) sv = -INFINITY;
                    scr[nt] = sv;
                }
                float mx = fmaxf(fmaxf(scr[0], scr[1]), fmaxf(scr[2], scr[3]));
                mx = fmaxf(mx, __shfl_xor(mx, 1));
                mx = fmaxf(mx, __shfl_xor(mx, 2));
                mx = fmaxf(mx, __shfl_xor(mx, 4));
                mx = fmaxf(mx, __shfl_xor(mx, 8));
                const float nm = fmaxf(m_r[reg], mx);
                const float a_ = __expf(m_r[reg] - nm);
                m_r[reg] = nm;
#pragma unroll
                for (int nt = 0; nt < 4; ++nt)
                    p_[nt][reg] = __expf(scr[nt] - nm);
                al[reg] = a_;
            }
#pragma unroll
            for (int nt = 0; nt < 4; ++nt)
#pragma unroll
                for (int reg = 0; reg < 4; ++reg) O[nt][reg] *= al[reg];

            // P: wave-private round-trip through EBuf's dead chunk-half (par cur)
            {
#pragma unroll
                for (int reg = 0; reg < 4; ++reg) {
                    ushort_t* pr = &EBuf[rw + reg][cur * 64];
                    pr[ 0 + lcol] = f2bf(p_[0][reg]);
                    pr[16 + lcol] = f2bf(p_[1][reg]);
                    pr[32 + lcol] = f2bf(p_[2][reg]);
                    pr[48 + lcol] = f2bf(p_[3][reg]);
                }
            }
            const short8 ap0 = *(const short8*)&EBuf[w * 16 + lcol][cur * 64 + quad * 8];
            const short8 ap1 = *(const short8*)&EBuf[w * 16 + lcol][cur * 64 + 32 + quad * 8];

            // row-sum of P via ones-MFMA (replaces shfl sum tree)
            f32x4 lacc = {0, 0, 0, 0};
            lacc = MFMA(ap0, ones8, lacc, 0, 0, 0);
            lacc = MFMA(ap1, ones8, lacc, 0, 0, 0);
#pragma unroll
            for (int reg = 0; reg < 4; ++reg)
                l_r[reg] = l_r[reg] * al[reg] + lacc[reg];

            // PV: swizzled Vt[cur] fragment reads
            {
#pragma unroll
                for (int nt = 0; nt < 4; ++nt) {
                    const int hs = nt * 16 + lcol;
                    const int f = ((hs >> 3) & 7) ^ (hs & 7);
                    const short8 bv0 = *(const short8*)&Vt[cur][hs * 64 + ((quad ^ f) << 3)];
                    const short8 bv1 = *(const short8*)&Vt[cur][hs * 64 + (((4 + quad) ^ f) << 3)];
                    O[nt] = MFMA(ap0, bv0, O[nt], 0, 0, 0);
                    O[nt] = MFMA(ap1, bv1, O[nt], 0, 0, 0);
                }
            }
        }

        float inv[4];
#pragma unroll
        for (int reg = 0; reg < 4; ++reg) inv[reg] = 1.f / l_r[reg];
#pragma unroll
        for (int nt = 0; nt < 4; ++nt) {
#pragma unroll
            for (int reg = 0; reg < 4; ++reg) {
                const int r = w * 16 + quad * 4 + reg;
                y[(((size_t)bb * L_ + qi0 + r) * H_ + hh) * HS_ + nt * 16 + lcol] =
                    f2bf(O[nt][reg] * inv[reg]);
            }
        }
    }
}

// ---------------------------------------------------------------------------
extern "C" void kernel_launch(void* const* d_in, const int* in_sizes, int n_in,
                              void* d_out, int out_size, void* d_ws, size_t ws_size,
                              hipStream_t stream)
{
    const float* x      = (const float*)d_in[0];   // [B,L,D]
    const float* W_attn = (const float*)d_in[1];   // [D,3D]
    const float* b_attn = (const float*)d_in[2];   // [3D]
    const float* W_proj = (const float*)d_in[3];   // [D,D]
    const float* b_proj = (const float*)d_in[4];   // [D]
    const float* Er     = (const float*)d_in[5];   // [L,HS] fp32
    float* out = (float*)d_out;

    const size_t per = (size_t)B_ * H_ * L_ * HS_;   // 8388608
    ushort_t* qb  = (ushort_t*)d_ws;                 // bf16 q|k|v
    ushort_t* kb  = qb + per;
    ushort_t* vb  = kb + per;
    ushort_t* yb  = vb + per;                        // bf16 [B][L][D]
    ushort_t* xb  = yb + per;                        // bf16 x
    ushort_t* wat = xb + per;                        // W_attn^T bf16 [3072][1024]
    ushort_t* wpt = wat + (size_t)3 * D_ * D_;       // W_proj^T bf16 [1024][1024]
    ushort_t* erb = wpt + (size_t)D_ * D_;           // Er bf16 [L][HS]
    unsigned int* ctr = (unsigned int*)(erb + (size_t)L_ * HS_);  // work counter

    dim3 blk(256);

    conv_to_bf16<<<dim3((B_ * L_ * D_) / 2048), blk, 0, stream>>>(x, xb);
    conv_to_bf16<<<dim3((L_ * HS_) / 2048), blk, 0, stream>>>(Er, erb);
    zero_u32<<<dim3(1), dim3(1), 0, stream>>>(ctr);
    transpose_to_bf16<<<dim3(3 * D_ / 64, D_ / 64), blk, 0, stream>>>(W_attn, wat, D_, 3 * D_);
    transpose_to_bf16<<<dim3(D_ / 64, D_ / 64), blk, 0, stream>>>(W_proj, wpt, D_, D_);

    qkv_mfma<<<dim3(3 * D_ / 128, B_ * L_ / 128), blk, 0, stream>>>(xb, wat, b_attn, qb);

    attn_mfma<<<dim3(PERSIST), blk, 0, stream>>>(qb, kb, vb, erb, ctr, yb);

    proj_mfma<<<dim3(D_ / 128, B_ * L_ / 128), blk, 0, stream>>>(yb, wpt, b_proj, out);
}

// Round 7
// 425.075 us; speedup vs baseline: 1.5105x; 1.2992x over previous
//
#include <hip/hip_runtime.h>
#include <hip/hip_bf16.h>
#include <math.h>

#define B_  4
#define L_  2048
#define D_  1024
#define H_  16
#define HS_ 64
#define SCALE 0.125f   // 1/sqrt(64)

typedef unsigned short ushort_t;
typedef __attribute__((ext_vector_type(8))) short short8;
typedef __attribute__((ext_vector_type(4))) float f32x4;

#define MFMA __builtin_amdgcn_mfma_f32_16x16x32_bf16

static __device__ __forceinline__ ushort_t f2bf(float f) {
    union { float f; unsigned int u; } cv; cv.f = f;
    unsigned int u = cv.u;
    unsigned int r = (u + 0x7FFFu + ((u >> 16) & 1u)) >> 16;   // RNE
    return (ushort_t)r;
}
static __device__ __forceinline__ float bf2f(ushort_t h) {
    union { float f; unsigned int u; } cv; cv.u = ((unsigned int)h) << 16;
    return cv.f;
}

static __device__ __forceinline__ void gload_lds16(const ushort_t* g, ushort_t* l) {
    __builtin_amdgcn_global_load_lds(
        (const __attribute__((address_space(1))) unsigned int*)g,
        (__attribute__((address_space(3))) unsigned int*)l, 16, 0, 0);
}

// ---------------------------------------------------------------------------
// Prep kernels: fp32 -> bf16 (x, Er), fp32 -> bf16 transposed (weights)
// ---------------------------------------------------------------------------
__global__ __launch_bounds__(256)
void conv_to_bf16(const float* __restrict__ x, ushort_t* __restrict__ xb)
{
    const size_t i = (size_t)blockIdx.x * 256 + threadIdx.x;   // 8 elems/thread
    const float4* src = (const float4*)x + i * 2;
    float4 a = src[0], b = src[1];
    ushort_t o[8] = {f2bf(a.x), f2bf(a.y), f2bf(a.z), f2bf(a.w),
                     f2bf(b.x), f2bf(b.y), f2bf(b.z), f2bf(b.w)};
    *(uint4*)(xb + i * 8) = *(uint4*)o;
}

__global__ void zero_u32(unsigned int* __restrict__ p) { *p = 0u; }

__global__ __launch_bounds__(256)
void transpose_to_bf16(const float* __restrict__ W, ushort_t* __restrict__ Wt,
                       int K, int N)   // W:[K][N] -> Wt:[N][K]
{
    __shared__ ushort_t tile[64][65];
    const int tid = threadIdx.x;
    const int n0 = blockIdx.x * 64, k0 = blockIdx.y * 64;
#pragma unroll
    for (int s = 0; s < 16; ++s) {
        const int idx = s * 256 + tid;
        const int kl = idx >> 6, nl = idx & 63;
        tile[nl][kl] = f2bf(W[(size_t)(k0 + kl) * N + n0 + nl]);
    }
    __syncthreads();
#pragma unroll
    for (int s = 0; s < 8; ++s) {
        const int idx = s * 256 + tid;
        const int nl = idx >> 5, kc = idx & 31;
        const unsigned int vlo = tile[nl][kc * 2];
        const unsigned int vhi = tile[nl][kc * 2 + 1];
        *(unsigned int*)(Wt + (size_t)(n0 + nl) * K + k0 + kc * 2) =
            vlo | (vhi << 16);
    }
}

// ---------------------------------------------------------------------------
// m97-style bf16 MFMA GEMM: C[M][N] = A[M][K] @ Bt[N][K]^T  (unchanged)
// ---------------------------------------------------------------------------
__global__ __launch_bounds__(256)
void qkv_mfma(const ushort_t* __restrict__ A, const ushort_t* __restrict__ Bt,
              const float* __restrict__ bias, ushort_t* __restrict__ qkv)
{
    __shared__ __align__(16) ushort_t As[128 * 64];
    __shared__ __align__(16) ushort_t Bs[128 * 64];

    const int tid = threadIdx.x;
    const int w = tid >> 6, lane = tid & 63, quad = lane >> 4, lcol = lane & 15;
    const int wr = w >> 1, wc = w & 1;
    const int m0 = blockIdx.y * 128, n0 = blockIdx.x * 128;
    const int K = D_;

    const int srow = tid >> 3;
    const int cg = (tid & 7) ^ (srow & 7);
    const ushort_t* gA = A + (size_t)(m0 + srow) * K + cg * 8;
    const ushort_t* gB = Bt + (size_t)(n0 + srow) * K + cg * 8;
    ushort_t* lA = As + tid * 8;
    ushort_t* lB = Bs + tid * 8;

    const int cs0 = ((quad) ^ (lcol & 7)) * 8;
    const int cs1 = ((4 + quad) ^ (lcol & 7)) * 8;

    f32x4 acc[4][4];
#pragma unroll
    for (int i = 0; i < 4; ++i)
#pragma unroll
        for (int j = 0; j < 4; ++j) acc[i][j] = (f32x4){0, 0, 0, 0};

    for (int k0 = 0; k0 < K; k0 += 64) {
        __syncthreads();
#pragma unroll
        for (int s = 0; s < 4; ++s) {
            gload_lds16(gA + k0 + (size_t)s * 32 * K, lA + s * 2048);
            gload_lds16(gB + k0 + (size_t)s * 32 * K, lB + s * 2048);
        }
        __syncthreads();
#pragma unroll
        for (int kk = 0; kk < 2; ++kk) {
            const int cs = kk ? cs1 : cs0;
            short8 af[4], bf[4];
#pragma unroll
            for (int i = 0; i < 4; ++i)
                af[i] = *(const short8*)&As[(wr * 64 + i * 16 + lcol) * 64 + cs];
#pragma unroll
            for (int j = 0; j < 4; ++j)
                bf[j] = *(const short8*)&Bs[(wc * 64 + j * 16 + lcol) * 64 + cs];
#pragma unroll
            for (int i = 0; i < 4; ++i)
#pragma unroll
                for (int j = 0; j < 4; ++j)
                    acc[i][j] = MFMA(af[i], bf[j], acc[i][j], 0, 0, 0);
        }
    }

    const size_t per = (size_t)B_ * H_ * L_ * HS_;
#pragma unroll
    for (int j = 0; j < 4; ++j) {
        const int col = n0 + wc * 64 + j * 16 + lcol;
        const float bv = bias[col];
        const int sel = col >> 10;
        const int within = col & 1023;
        const int hh = within >> 6, hs = within & 63;
        ushort_t* base = qkv + (size_t)sel * per;
#pragma unroll
        for (int i = 0; i < 4; ++i) {
#pragma unroll
            for (int reg = 0; reg < 4; ++reg) {
                const int row = m0 + wr * 64 + i * 16 + quad * 4 + reg;
                const int bb = row >> 11, ll = row & 2047;
                base[(((size_t)(bb * H_ + hh)) * L_ + ll) * HS_ + hs] =
                    f2bf(acc[i][j][reg] + bv);
            }
        }
    }
}

__global__ __launch_bounds__(256)
void proj_mfma(const ushort_t* __restrict__ A, const ushort_t* __restrict__ Bt,
               const float* __restrict__ bias, float* __restrict__ C)
{
    __shared__ __align__(16) ushort_t As[128 * 64];
    __shared__ __align__(16) ushort_t Bs[128 * 64];

    const int tid = threadIdx.x;
    const int w = tid >> 6, lane = tid & 63, quad = lane >> 4, lcol = lane & 15;
    const int wr = w >> 1, wc = w & 1;
    const int m0 = blockIdx.y * 128, n0 = blockIdx.x * 128;
    const int K = D_;
    const int N = D_;

    const int srow = tid >> 3;
    const int cg = (tid & 7) ^ (srow & 7);
    const ushort_t* gA = A + (size_t)(m0 + srow) * K + cg * 8;
    const ushort_t* gB = Bt + (size_t)(n0 + srow) * K + cg * 8;
    ushort_t* lA = As + tid * 8;
    ushort_t* lB = Bs + tid * 8;

    const int cs0 = ((quad) ^ (lcol & 7)) * 8;
    const int cs1 = ((4 + quad) ^ (lcol & 7)) * 8;

    f32x4 acc[4][4];
#pragma unroll
    for (int i = 0; i < 4; ++i)
#pragma unroll
        for (int j = 0; j < 4; ++j) acc[i][j] = (f32x4){0, 0, 0, 0};

    for (int k0 = 0; k0 < K; k0 += 64) {
        __syncthreads();
#pragma unroll
        for (int s = 0; s < 4; ++s) {
            gload_lds16(gA + k0 + (size_t)s * 32 * K, lA + s * 2048);
            gload_lds16(gB + k0 + (size_t)s * 32 * K, lB + s * 2048);
        }
        __syncthreads();
#pragma unroll
        for (int kk = 0; kk < 2; ++kk) {
            const int cs = kk ? cs1 : cs0;
            short8 af[4], bf[4];
#pragma unroll
            for (int i = 0; i < 4; ++i)
                af[i] = *(const short8*)&As[(wr * 64 + i * 16 + lcol) * 64 + cs];
#pragma unroll
            for (int j = 0; j < 4; ++j)
                bf[j] = *(const short8*)&Bs[(wc * 64 + j * 16 + lcol) * 64 + cs];
#pragma unroll
            for (int i = 0; i < 4; ++i)
#pragma unroll
                for (int j = 0; j < 4; ++j)
                    acc[i][j] = MFMA(af[i], bf[j], acc[i][j], 0, 0, 0);
        }
    }

#pragma unroll
    for (int j = 0; j < 4; ++j) {
        const int col = n0 + wc * 64 + j * 16 + lcol;
        const float bv = bias[col];
#pragma unroll
        for (int i = 0; i < 4; ++i) {
#pragma unroll
            for (int reg = 0; reg < 4; ++reg) {
                const int row = m0 + wr * 64 + i * 16 + quad * 4 + reg;
                C[(size_t)row * N + col] = acc[i][j][reg] + bv;
            }
        }
    }
}

// ---------------------------------------------------------------------------
// MFMA flash attention, v8: exact R4 (v5, 273 us best-known) + ONE delta:
//  * ones-MFMA row-sum of P replaces the 4-deep __shfl_xor sum tree
//    (-16 DS-pipe shfl/iter, shorter softmax dependency chain; +2 MFMA on
//    the 8%-utilized matrix pipe; numerics validated in v6/v7).
//  * Everything else identical to R4: Kd via global_load_lds (K-in-regs is
//    DEAD — spills at any launch bound, R5/R6 evidence), erf register
//    prefetch, Vt packed b32 swizzled writes, EBuf P-alias, persistent
//    768-block work stealing, launch_bounds(256,3).
// ---------------------------------------------------------------------------
#define QT 64
#define KT 64
#define NITEMS (B_ * H_ * (L_ / QT))   // 2048
#define PERSIST 768

__global__ __launch_bounds__(256, 3)
void attn_mfma(const ushort_t* __restrict__ q, const ushort_t* __restrict__ k,
               const ushort_t* __restrict__ v, const ushort_t* __restrict__ Erb,
               unsigned int* __restrict__ ctr, ushort_t* __restrict__ y)
{
    __shared__ __align__(16) ushort_t Kd[2][64 * 64];   // K tiles, swizzled
    __shared__ __align__(16) ushort_t Vt[2][64 * 64];   // [hs][key], swizzled
    __shared__ __align__(16) ushort_t EBuf[64][136];    // rolling QEr + P alias
    __shared__ int s_item;

    const int tid  = threadIdx.x;
    const int w    = tid >> 6;
    const int lane = tid & 63;
    const int quad = lane >> 4;
    const int lcol = lane & 15;
    const int rw   = w * 16 + quad * 4;

    // K async-staging constants (GEMM staging path)
    const int s_row = tid >> 3;                    // 0..31
    const int cgc   = (tid & 7) ^ (s_row & 7);     // swizzled source chunk
    // V transpose-staging constants: thread -> (key pair, hs block)
    const int vkp = (tid & 31) * 2;                // key pair base (even)
    const int vhb = (tid >> 5) * 8;                // hs block
    const int vkc = vkp >> 3, vks = vkp & 7;
    // fragment chunk offsets for Kd reads
    const int fs0 = ((quad) ^ (lcol & 7)) * 8;
    const int fs1 = ((4 + quad) ^ (lcol & 7)) * 8;

    const short8 ones8 = {(short)0x3F80, (short)0x3F80, (short)0x3F80, (short)0x3F80,
                          (short)0x3F80, (short)0x3F80, (short)0x3F80, (short)0x3F80};

    for (;;) {
        if (tid == 0) s_item = (int)atomicAdd(ctr, 1u);
        __syncthreads();                 // broadcast item; also fences LDS reuse
        const int idx = s_item;
        if (idx >= NITEMS) break;

        // decode: windows of 8 bh x 32 qt, heavy-first within window
        const int wnd = idx >> 8;                 // 0..7
        const int sub = idx & 255;
        const int qt  = 31 - (sub >> 3);
        const int bh  = wnd * 8 + (sub & 7);
        const int qi0 = qt * QT;
        const int bb  = bh >> 4;
        const int hh  = bh & 15;
        const int cband = L_ - QT - qi0;

        const ushort_t* qp = q + (size_t)bh * L_ * HS_;
        const ushort_t* kp = k + (size_t)bh * L_ * HS_;
        const ushort_t* vp = v + (size_t)bh * L_ * HS_;

        // Q fragments (one-time per item, direct from global)
        const ushort_t* qrow = qp + (size_t)(qi0 + w * 16 + lcol) * HS_;
        const short8 aq0 = *(const short8*)(qrow + quad * 8);
        const short8 aq1 = *(const short8*)(qrow + 32 + quad * 8);

        // ---- prologue ----
        // EBuf chunk 0 via direct-global Er MFMAs (one-time)
        {
            const ushort_t* eb = Erb + (size_t)cband * HS_;
            f32x4 e0 = {0,0,0,0}, e1 = {0,0,0,0}, e2 = {0,0,0,0}, e3 = {0,0,0,0};
            e0 = MFMA(aq0, *(const short8*)(eb + (size_t)( 0 + lcol) * HS_ +      quad * 8), e0, 0,0,0);
            e1 = MFMA(aq0, *(const short8*)(eb + (size_t)(16 + lcol) * HS_ +      quad * 8), e1, 0,0,0);
            e2 = MFMA(aq0, *(const short8*)(eb + (size_t)(32 + lcol) * HS_ +      quad * 8), e2, 0,0,0);
            e3 = MFMA(aq0, *(const short8*)(eb + (size_t)(48 + lcol) * HS_ +      quad * 8), e3, 0,0,0);
            e0 = MFMA(aq1, *(const short8*)(eb + (size_t)( 0 + lcol) * HS_ + 32 + quad * 8), e0, 0,0,0);
            e1 = MFMA(aq1, *(const short8*)(eb + (size_t)(16 + lcol) * HS_ + 32 + quad * 8), e1, 0,0,0);
            e2 = MFMA(aq1, *(const short8*)(eb + (size_t)(32 + lcol) * HS_ + 32 + quad * 8), e2, 0,0,0);
            e3 = MFMA(aq1, *(const short8*)(eb + (size_t)(48 + lcol) * HS_ + 32 + quad * 8), e3, 0,0,0);
#pragma unroll
            for (int reg = 0; reg < 4; ++reg) {
                EBuf[rw + reg][ 0 + lcol] = f2bf(e0[reg]);
                EBuf[rw + reg][16 + lcol] = f2bf(e1[reg]);
                EBuf[rw + reg][32 + lcol] = f2bf(e2[reg]);
                EBuf[rw + reg][48 + lcol] = f2bf(e3[reg]);
            }
        }
        // stage K tile 0 -> Kd[0]
        {
            const ushort_t* g = kp + (size_t)s_row * HS_ + cgc * 8;
            gload_lds16(g,            &Kd[0][tid * 8]);
            gload_lds16(g + 32 * HS_, &Kd[0][2048 + tid * 8]);
        }
        // Er fragments for chunk 1 -> regs (row-clamped)
        short8 erf[8];
#pragma unroll
        for (int nt = 0; nt < 4; ++nt) {
            int r = cband + 64 + nt * 16 + lcol;
            if (r > L_ - 1) r = L_ - 1;
            const ushort_t* p = Erb + (size_t)r * HS_ + quad * 8;
            erf[nt * 2]     = *(const short8*)p;
            erf[nt * 2 + 1] = *(const short8*)(p + 32);
        }
        // V tile 0 -> Vt[0] (sync reg round-trip, packed b32 swizzled write)
        {
            const ushort_t* src = vp + (size_t)vkp * HS_ + vhb;
            uint4 a = *(const uint4*)src;
            uint4 b = *(const uint4*)(src + HS_);
            const ushort_t* pa = (const ushort_t*)&a;
            const ushort_t* pb = (const ushort_t*)&b;
#pragma unroll
            for (int u = 0; u < 8; ++u) {
                const int hs = vhb + u;
                const int f = ((hs >> 3) & 7) ^ (hs & 7);
                const unsigned int val = (unsigned int)pa[u] | ((unsigned int)pb[u] << 16);
                *(unsigned int*)&Vt[0][hs * 64 + ((vkc ^ f) << 3) + vks] = val;
            }
        }
        // V tile 1 -> regs (unused if qt==0; rows always in-bounds)
        uint4 va, vb;
        {
            const ushort_t* src = vp + (size_t)(KT + vkp) * HS_ + vhb;
            va = *(const uint4*)src; vb = *(const uint4*)(src + HS_);
        }

        f32x4 O[4];
#pragma unroll
        for (int nt = 0; nt < 4; ++nt) O[nt] = (f32x4){0, 0, 0, 0};
        float m_r[4] = {-INFINITY, -INFINITY, -INFINITY, -INFINITY};
        float l_r[4] = {0, 0, 0, 0};

        for (int kt = 0; kt <= qt; ++kt) {
            const int kj0 = kt * KT;
            const int cur = kt & 1, nxt = cur ^ 1;

            __syncthreads();   // drains last iter's async stages; orders buffers

            if (kt < qt) {
                // write Vt[nxt] <- V tile kt+1 (regs loaded last iter)
                {
                    const ushort_t* pa = (const ushort_t*)&va;
                    const ushort_t* pb = (const ushort_t*)&vb;
#pragma unroll
                    for (int u = 0; u < 8; ++u) {
                        const int hs = vhb + u;
                        const int f = ((hs >> 3) & 7) ^ (hs & 7);
                        const unsigned int val = (unsigned int)pa[u] | ((unsigned int)pb[u] << 16);
                        *(unsigned int*)&Vt[nxt][hs * 64 + ((vkc ^ f) << 3) + vks] = val;
                    }
                }
                // issue V tile kt+2 -> regs (row-clamped)
                {
                    int kj2 = (kt + 2) * KT;
                    if (kj2 > L_ - KT) kj2 = L_ - KT;
                    const ushort_t* src = vp + (size_t)(kj2 + vkp) * HS_ + vhb;
                    va = *(const uint4*)src; vb = *(const uint4*)(src + HS_);
                }
                // issue K tile kt+1 -> Kd[nxt]
                {
                    const ushort_t* g = kp + (size_t)((kt + 1) * KT + s_row) * HS_ + cgc * 8;
                    gload_lds16(g,            &Kd[nxt][tid * 8]);
                    gload_lds16(g + 32 * HS_, &Kd[nxt][2048 + tid * 8]);
                }
            }

            // ---- QEr chunk kt+1 from erf regs ----
            f32x4 e0 = {0,0,0,0}, e1 = {0,0,0,0}, e2 = {0,0,0,0}, e3 = {0,0,0,0};
            e0 = MFMA(aq0, erf[0], e0, 0,0,0);
            e1 = MFMA(aq0, erf[2], e1, 0,0,0);
            e2 = MFMA(aq0, erf[4], e2, 0,0,0);
            e3 = MFMA(aq0, erf[6], e3, 0,0,0);
            e0 = MFMA(aq1, erf[1], e0, 0,0,0);
            e1 = MFMA(aq1, erf[3], e1, 0,0,0);
            e2 = MFMA(aq1, erf[5], e2, 0,0,0);
            e3 = MFMA(aq1, erf[7], e3, 0,0,0);

            // reload erf <- Er fragments for chunk kt+2 (WAR; lands next iter)
            {
                const int ebase = cband + (kt + 2) * 64;
#pragma unroll
                for (int nt = 0; nt < 4; ++nt) {
                    int r = ebase + nt * 16 + lcol;
                    if (r > L_ - 1) r = L_ - 1;
                    const ushort_t* p = Erb + (size_t)r * HS_ + quad * 8;
                    erf[nt * 2]     = *(const short8*)p;
                    erf[nt * 2 + 1] = *(const short8*)(p + 32);
                }
            }

            {
                const int par = nxt * 64;   // chunk kt+1
#pragma unroll
                for (int reg = 0; reg < 4; ++reg) {
                    EBuf[rw + reg][par +  0 + lcol] = f2bf(e0[reg]);
                    EBuf[rw + reg][par + 16 + lcol] = f2bf(e1[reg]);
                    EBuf[rw + reg][par + 32 + lcol] = f2bf(e2[reg]);
                    EBuf[rw + reg][par + 48 + lcol] = f2bf(e3[reg]);
                }
            }

            // ---- scores from Kd[cur] ----
            f32x4 s0 = {0,0,0,0}, s1 = {0,0,0,0}, s2 = {0,0,0,0}, s3 = {0,0,0,0};
            s0 = MFMA(aq0, *(const short8*)&Kd[cur][( 0 + lcol) * 64 + fs0], s0, 0,0,0);
            s1 = MFMA(aq0, *(const short8*)&Kd[cur][(16 + lcol) * 64 + fs0], s1, 0,0,0);
            s2 = MFMA(aq0, *(const short8*)&Kd[cur][(32 + lcol) * 64 + fs0], s2, 0,0,0);
            s3 = MFMA(aq0, *(const short8*)&Kd[cur][(48 + lcol) * 64 + fs0], s3, 0,0,0);
            s0 = MFMA(aq1, *(const short8*)&Kd[cur][( 0 + lcol) * 64 + fs1], s0, 0,0,0);
            s1 = MFMA(aq1, *(const short8*)&Kd[cur][(16 + lcol) * 64 + fs1], s1, 0,0,0);
            s2 = MFMA(aq1, *(const short8*)&Kd[cur][(32 + lcol) * 64 + fs1], s2, 0,0,0);
            s3 = MFMA(aq1, *(const short8*)&Kd[cur][(48 + lcol) * 64 + fs1], s3, 0,0,0);

            float p_[4][4];
            float al[4];
            const float sq[4][4] = {
                {s0[0], s0[1], s0[2], s0[3]},
                {s1[0], s1[1], s1[2], s1[3]},
                {s2[0], s2[1], s2[2], s2[3]},
                {s3[0], s3[1], s3[2], s3[3]}};
#pragma unroll
            for (int reg = 0; reg < 4; ++reg) {
                const int r = w * 16 + quad * 4 + reg;
                float scr[4];
#pragma unroll
                for (int nt = 0; nt < 4; ++nt) {
                    const int jl = nt * 16 + lcol;
                    const int c = (63 - r + jl + kj0) & 127;
                    float sv = (sq[nt][reg] + bf2f(EBuf[r][c])) * SCALE;
                    if (kt == qt && jl > r) sv = -INFINITY;
                    scr[nt] = sv;
                }
                float mx = fmaxf(fmaxf(scr[0], scr[1]), fmaxf(scr[2], scr[3]));
                mx = fmaxf(mx, __shfl_xor(mx, 1));
                mx = fmaxf(mx, __shfl_xor(mx, 2));
                mx = fmaxf(mx, __shfl_xor(mx, 4));
                mx = fmaxf(mx, __shfl_xor(mx, 8));
                const float nm = fmaxf(m_r[reg], mx);
                const float a_ = __expf(m_r[reg] - nm);
                m_r[reg] = nm;
#pragma unroll
                for (int nt = 0; nt < 4; ++nt)
                    p_[nt][reg] = __expf(scr[nt] - nm);
                al[reg] = a_;
            }
#pragma unroll
            for (int nt = 0; nt < 4; ++nt)
#pragma unroll
                for (int reg = 0; reg < 4; ++reg) O[nt][reg] *= al[reg];

            // P: wave-private round-trip through EBuf's dead chunk-half (par cur)
            {
#pragma unroll
                for (int reg = 0; reg < 4; ++reg) {
                    ushort_t* pr = &EBuf[rw + reg][cur * 64];
                    pr[ 0 + lcol] = f2bf(p_[0][reg]);
                    pr[16 + lcol] = f2bf(p_[1][reg]);
                    pr[32 + lcol] = f2bf(p_[2][reg]);
                    pr[48 + lcol] = f2bf(p_[3][reg]);
                }
            }
            const short8 ap0 = *(const short8*)&EBuf[w * 16 + lcol][cur * 64 + quad * 8];
            const short8 ap1 = *(const short8*)&EBuf[w * 16 + lcol][cur * 64 + 32 + quad * 8];

            // row-sum of P via ones-MFMA (replaces the shfl sum tree)
            f32x4 lacc = {0, 0, 0, 0};
            lacc = MFMA(ap0, ones8, lacc, 0, 0, 0);
            lacc = MFMA(ap1, ones8, lacc, 0, 0, 0);
#pragma unroll
            for (int reg = 0; reg < 4; ++reg)
                l_r[reg] = l_r[reg] * al[reg] + lacc[reg];

            // PV: swizzled Vt[cur] fragment reads
            {
#pragma unroll
                for (int nt = 0; nt < 4; ++nt) {
                    const int hs = nt * 16 + lcol;
                    const int f = ((hs >> 3) & 7) ^ (hs & 7);
                    const short8 bv0 = *(const short8*)&Vt[cur][hs * 64 + ((quad ^ f) << 3)];
                    const short8 bv1 = *(const short8*)&Vt[cur][hs * 64 + (((4 + quad) ^ f) << 3)];
                    O[nt] = MFMA(ap0, bv0, O[nt], 0, 0, 0);
                    O[nt] = MFMA(ap1, bv1, O[nt], 0, 0, 0);
                }
            }
        }

        float inv[4];
#pragma unroll
        for (int reg = 0; reg < 4; ++reg) inv[reg] = 1.f / l_r[reg];
#pragma unroll
        for (int nt = 0; nt < 4; ++nt) {
#pragma unroll
            for (int reg = 0; reg < 4; ++reg) {
                const int r = w * 16 + quad * 4 + reg;
                y[(((size_t)bb * L_ + qi0 + r) * H_ + hh) * HS_ + nt * 16 + lcol] =
                    f2bf(O[nt][reg] * inv[reg]);
            }
        }
    }
}

// ---------------------------------------------------------------------------
extern "C" void kernel_launch(void* const* d_in, const int* in_sizes, int n_in,
                              void* d_out, int out_size, void* d_ws, size_t ws_size,
                              hipStream_t stream)
{
    const float* x      = (const float*)d_in[0];   // [B,L,D]
    const float* W_attn = (const float*)d_in[1];   // [D,3D]
    const float* b_attn = (const float*)d_in[2];   // [3D]
    const float* W_proj = (const float*)d_in[3];   // [D,D]
    const float* b_proj = (const float*)d_in[4];   // [D]
    const float* Er     = (const float*)d_in[5];   // [L,HS] fp32
    float* out = (float*)d_out;

    const size_t per = (size_t)B_ * H_ * L_ * HS_;   // 8388608
    ushort_t* qb  = (ushort_t*)d_ws;                 // bf16 q|k|v
    ushort_t* kb  = qb + per;
    ushort_t* vb  = kb + per;
    ushort_t* yb  = vb + per;                        // bf16 [B][L][D]
    ushort_t* xb  = yb + per;                        // bf16 x
    ushort_t* wat = xb + per;                        // W_attn^T bf16 [3072][1024]
    ushort_t* wpt = wat + (size_t)3 * D_ * D_;       // W_proj^T bf16 [1024][1024]
    ushort_t* erb = wpt + (size_t)D_ * D_;           // Er bf16 [L][HS]
    unsigned int* ctr = (unsigned int*)(erb + (size_t)L_ * HS_);  // work counter

    dim3 blk(256);

    conv_to_bf16<<<dim3((B_ * L_ * D_) / 2048), blk, 0, stream>>>(x, xb);
    conv_to_bf16<<<dim3((L_ * HS_) / 2048), blk, 0, stream>>>(Er, erb);
    zero_u32<<<dim3(1), dim3(1), 0, stream>>>(ctr);
    transpose_to_bf16<<<dim3(3 * D_ / 64, D_ / 64), blk, 0, stream>>>(W_attn, wat, D_, 3 * D_);
    transpose_to_bf16<<<dim3(D_ / 64, D_ / 64), blk, 0, stream>>>(W_proj, wpt, D_, D_);

    qkv_mfma<<<dim3(3 * D_ / 128, B_ * L_ / 128), blk, 0, stream>>>(xb, wat, b_attn, qb);

    attn_mfma<<<dim3(PERSIST), blk, 0, stream>>>(qb, kb, vb, erb, ctr, yb);

    proj_mfma<<<dim3(D_ / 128, B_ * L_ / 128), blk, 0, stream>>>(yb, wpt, b_proj, out);
}